// Round 4
// baseline (324.696 us; speedup 1.0000x reference)
//
#include <hip/hip_runtime.h>
#include <math.h>

// Problem constants (fixed by setup_inputs)
#define DD 128
#define NROWS 769          // 256 input-enc + 256 output-enc + 256 gate + 1 zero
#define T_TOTAL 524288

typedef float vfloat4 __attribute__((ext_vector_type(4)));
typedef int   vint4   __attribute__((ext_vector_type(4)));

// ws layout (floats):
//   Wt      [3][128][128] @ 0          (Wt[part][k][j] = W[j][part*128+k])
//   Psrc    [NROWS][DD]   @ 49152
//   Pdst    [NROWS][DD]   @ 49152 +  98432
//   Prel    [2][DD]       @ 49152 + 196864
//   pk      [T] ints      @ 49152 + 197120   (packed fs|fd<<10|rel<<20)
// total ~= 3 MB (fits easily in ws)

#define WT_OFF    0
#define PSRC_OFF  (3 * DD * DD)
#define PDST_OFF  (PSRC_OFF + NROWS * DD)
#define PREL_OFF  (PDST_OFF + NROWS * DD)
#define PK_OFF    (PREL_OFF + 2 * DD)

// Fused pre-pass: blocks [0,128) transpose W; blocks [128, 128+1024) pack the
// 5 index arrays into one int per row (int4-vectorized, coalesced). The two
// halves are independent and overlap in one dispatch.
__global__ __launch_bounds__(DD) void pre(
    const float* __restrict__ W, float* __restrict__ Wt,
    const int* __restrict__ src_idx, const int* __restrict__ src_type,
    const int* __restrict__ rel, const int* __restrict__ dst_idx,
    const int* __restrict__ dst_type, int* __restrict__ pk) {
    int bid = blockIdx.x;
    int tid = threadIdx.x;
    if (bid < DD) {
        int k = bid;   // 0..127
        int j = tid;   // 0..127
        Wt[0 * DD * DD + k * DD + j] = W[j * 384 + k];         // src part
        Wt[1 * DD * DD + k * DD + j] = W[j * 384 + 128 + k];   // rel part
        Wt[2 * DD * DD + k * DD + j] = W[j * 384 + 256 + k];   // dst part
    } else {
        int t4 = (bid - DD) * DD + tid;    // which int4 group of T/4
        vint4 si = ((const vint4*)src_idx)[t4];
        vint4 st = ((const vint4*)src_type)[t4];
        vint4 rl = ((const vint4*)rel)[t4];
        vint4 di = ((const vint4*)dst_idx)[t4];
        vint4 dt = ((const vint4*)dst_type)[t4];
        vint4 o;
#pragma unroll
        for (int m = 0; m < 4; ++m) {
            int fs = (st[m] == 3) ? 768 : st[m] * 256 + si[m];  // zero row 768
            int fd = (dt[m] == 3) ? 768 : dt[m] * 256 + di[m];
            o[m] = fs | (fd << 10) | (rl[m] << 20);
        }
        ((vint4*)pk)[t4] = o;
    }
}

// One block per table row (769 node rows + 2 rel rows). Builds the embedding
// row in LDS, then computes the W projection with coalesced Wt reads.
__global__ __launch_bounds__(DD) void prep(
    const float* __restrict__ gate_emb, const float* __restrict__ edge_emb,
    const float* __restrict__ b, const float* __restrict__ Wt,
    float* __restrict__ Psrc, float* __restrict__ Pdst,
    float* __restrict__ Prel) {
    __shared__ float row[DD];
    int r = blockIdx.x;
    int j = threadIdx.x;

    if (r < NROWS) {
        float v;
        if (r < 512) {
            int p = r & 255;   // input/output sinusoid tables are identical
            int i = j >> 1;
            float div = expf(-logf(10000.0f) * (2.0f * (float)i) / 128.0f);
            float ang = (float)p * div;
            v = (j & 1) ? cosf(ang) : sinf(ang);
        } else if (r < 768) {
            v = gate_emb[(r - 512) * DD + j];
        } else {
            v = 0.0f;
        }
        row[j] = v;
        __syncthreads();
        const float* Ws = Wt;                 // src part
        const float* Wd = Wt + 2 * DD * DD;   // dst part
        float s = 0.0f, d = 0.0f;
#pragma unroll 8
        for (int k = 0; k < DD; ++k) {
            float e = row[k];                          // LDS broadcast (free)
            s = fmaf(e, Ws[k * DD + j], s);            // coalesced
            d = fmaf(e, Wd[k * DD + j], d);
        }
        Psrc[r * DD + j] = s;
        Pdst[r * DD + j] = d;
    } else {
        int rr = r - NROWS;                   // 0..1
        row[j] = edge_emb[rr * DD + j];
        __syncthreads();
        const float* Wr = Wt + 1 * DD * DD;   // rel part
        float s = b[j];
#pragma unroll 8
        for (int k = 0; k < DD; ++k) s = fmaf(row[k], Wr[k * DD + j], s);
        Prel[rr * DD + j] = s;
    }
}

// out[t] = Psrc[fs(t)] + Prel[rel(t)] + Pdst[fd(t)]
// Block = 256 threads = 8 lane-groups of 32; block covers 64 rows, lane-group
// g owns the 8 contiguous rows rowBase+g*8 .. +7. Indices come pre-packed
// from the pk array (2 MB, L2-resident). Prel has only 2 rows: both loaded
// per-thread and selected with cndmask instead of gathered.
//
// ROUND-4 A/B: plain stores instead of __builtin_nontemporal_store. Theory:
// the fill kernels reach 6.5 TB/s with PLAIN stores; if the nt path skips L2
// write-combining, the 268 MB output stream is what holds gather ~2x above
// its write floor. The P-tables (0.8 MB) are cheap to re-fetch from L3 even
// if the write stream evicts them from L2.
__global__ __launch_bounds__(256) void gather_add(
    const int* __restrict__ pk,
    const vfloat4* __restrict__ Psrc, const vfloat4* __restrict__ Pdst,
    const vfloat4* __restrict__ Prel, vfloat4* __restrict__ out) {
    int tid  = threadIdx.x;
    int lane = tid & 31;                 // which float4 of the 128-dim row
    int grp  = tid >> 5;                 // 0..7
    int rowBase = blockIdx.x * 64;

    vint4 pkA = ((const vint4*)pk)[(rowBase >> 2) + grp * 2];
    vint4 pkB = ((const vint4*)pk)[(rowBase >> 2) + grp * 2 + 1];
    // Both rel rows (incl. bias) live in L1/L2 — load once, select per row.
    vfloat4 rel0 = Prel[lane];
    vfloat4 rel1 = Prel[32 + lane];

    int p[8] = {pkA[0], pkA[1], pkA[2], pkA[3],
                pkB[0], pkB[1], pkB[2], pkB[3]};

    vfloat4 a[8], c[8];
#pragma unroll
    for (int i = 0; i < 8; ++i) a[i] = Psrc[(p[i] & 1023) * 32 + lane];
#pragma unroll
    for (int i = 0; i < 8; ++i) c[i] = Pdst[((p[i] >> 10) & 1023) * 32 + lane];

    int rowT = rowBase + grp * 8;
#pragma unroll
    for (int i = 0; i < 8; ++i) {
        vfloat4 o = a[i] + c[i] + ((p[i] >> 20) ? rel1 : rel0);
        out[(rowT + i) * 32 + lane] = o;   // plain store (A/B vs nt)
    }
}

extern "C" void kernel_launch(void* const* d_in, const int* in_sizes, int n_in,
                              void* d_out, int out_size, void* d_ws, size_t ws_size,
                              hipStream_t stream) {
    const float* gate_emb = (const float*)d_in[0];
    const float* edge_emb = (const float*)d_in[1];
    const float* W        = (const float*)d_in[2];
    const float* b        = (const float*)d_in[3];
    const int* src_idx    = (const int*)d_in[4];
    const int* src_type   = (const int*)d_in[5];
    const int* rel        = (const int*)d_in[6];
    const int* dst_idx    = (const int*)d_in[7];
    const int* dst_type   = (const int*)d_in[8];
    // d_in[9], d_in[10]: num_input_nodes / num_output_nodes == 256 (fixed)

    float* ws   = (float*)d_ws;
    float* Wt   = ws + WT_OFF;
    float* Psrc = ws + PSRC_OFF;
    float* Pdst = ws + PDST_OFF;
    float* Prel = ws + PREL_OFF;
    int*   pk   = (int*)(ws + PK_OFF);

    // pre: 128 transpose blocks + T/(128*4)=1024 pack blocks, one dispatch.
    pre<<<DD + T_TOTAL / (DD * 4), DD, 0, stream>>>(
        W, Wt, src_idx, src_type, rel, dst_idx, dst_type, pk);
    prep<<<NROWS + 2, DD, 0, stream>>>(gate_emb, edge_emb, b, Wt,
                                       Psrc, Pdst, Prel);
    gather_add<<<T_TOTAL / 64, 256, 0, stream>>>(
        pk, (const vfloat4*)Psrc, (const vfloat4*)Pdst,
        (const vfloat4*)Prel, (vfloat4*)d_out);
}

// Round 5
// 318.528 us; speedup vs baseline: 1.0194x; 1.0194x over previous
//
#include <hip/hip_runtime.h>
#include <math.h>

// Problem constants (fixed by setup_inputs)
#define DD 128
#define NROWS 769          // 256 input-enc + 256 output-enc + 256 gate + 1 zero
#define T_TOTAL 524288

typedef float vfloat4 __attribute__((ext_vector_type(4)));
typedef int   vint4   __attribute__((ext_vector_type(4)));

// ws layout (floats):
//   Wt      [3][128][128] @ 0          (Wt[part][k][j] = W[j][part*128+k])
//   Psrc    [NROWS][DD]   @ 49152
//   Pdst    [NROWS][DD]   @ 49152 +  98432
//   Prel    [2][DD]       @ 49152 + 196864
//   pk      [T] ints      @ 49152 + 197120   (packed fs|fd<<10|rel<<20)
// total ~= 3 MB (fits easily in ws)

#define WT_OFF    0
#define PSRC_OFF  (3 * DD * DD)
#define PDST_OFF  (PSRC_OFF + NROWS * DD)
#define PREL_OFF  (PDST_OFF + NROWS * DD)
#define PK_OFF    (PREL_OFF + 2 * DD)

// Fused pre-pass: blocks [0,128) transpose W; blocks [128, 128+1024) pack the
// 5 index arrays into one int per row (int4-vectorized, coalesced). The two
// halves are independent and overlap in one dispatch.
__global__ __launch_bounds__(DD) void pre(
    const float* __restrict__ W, float* __restrict__ Wt,
    const int* __restrict__ src_idx, const int* __restrict__ src_type,
    const int* __restrict__ rel, const int* __restrict__ dst_idx,
    const int* __restrict__ dst_type, int* __restrict__ pk) {
    int bid = blockIdx.x;
    int tid = threadIdx.x;
    if (bid < DD) {
        int k = bid;   // 0..127
        int j = tid;   // 0..127
        Wt[0 * DD * DD + k * DD + j] = W[j * 384 + k];         // src part
        Wt[1 * DD * DD + k * DD + j] = W[j * 384 + 128 + k];   // rel part
        Wt[2 * DD * DD + k * DD + j] = W[j * 384 + 256 + k];   // dst part
    } else {
        int t4 = (bid - DD) * DD + tid;    // which int4 group of T/4
        vint4 si = ((const vint4*)src_idx)[t4];
        vint4 st = ((const vint4*)src_type)[t4];
        vint4 rl = ((const vint4*)rel)[t4];
        vint4 di = ((const vint4*)dst_idx)[t4];
        vint4 dt = ((const vint4*)dst_type)[t4];
        vint4 o;
#pragma unroll
        for (int m = 0; m < 4; ++m) {
            int fs = (st[m] == 3) ? 768 : st[m] * 256 + si[m];  // zero row 768
            int fd = (dt[m] == 3) ? 768 : dt[m] * 256 + di[m];
            o[m] = fs | (fd << 10) | (rl[m] << 20);
        }
        ((vint4*)pk)[t4] = o;
    }
}

// One block per table row (769 node rows + 2 rel rows). Builds the embedding
// row in LDS, then computes the W projection with coalesced Wt reads.
__global__ __launch_bounds__(DD) void prep(
    const float* __restrict__ gate_emb, const float* __restrict__ edge_emb,
    const float* __restrict__ b, const float* __restrict__ Wt,
    float* __restrict__ Psrc, float* __restrict__ Pdst,
    float* __restrict__ Prel) {
    __shared__ float row[DD];
    int r = blockIdx.x;
    int j = threadIdx.x;

    if (r < NROWS) {
        float v;
        if (r < 512) {
            int p = r & 255;   // input/output sinusoid tables are identical
            int i = j >> 1;
            float div = expf(-logf(10000.0f) * (2.0f * (float)i) / 128.0f);
            float ang = (float)p * div;
            v = (j & 1) ? cosf(ang) : sinf(ang);
        } else if (r < 768) {
            v = gate_emb[(r - 512) * DD + j];
        } else {
            v = 0.0f;
        }
        row[j] = v;
        __syncthreads();
        const float* Ws = Wt;                 // src part
        const float* Wd = Wt + 2 * DD * DD;   // dst part
        float s = 0.0f, d = 0.0f;
#pragma unroll 8
        for (int k = 0; k < DD; ++k) {
            float e = row[k];                          // LDS broadcast (free)
            s = fmaf(e, Ws[k * DD + j], s);            // coalesced
            d = fmaf(e, Wd[k * DD + j], d);
        }
        Psrc[r * DD + j] = s;
        Pdst[r * DD + j] = d;
    } else {
        int rr = r - NROWS;                   // 0..1
        row[j] = edge_emb[rr * DD + j];
        __syncthreads();
        const float* Wr = Wt + 1 * DD * DD;   // rel part
        float s = b[j];
#pragma unroll 8
        for (int k = 0; k < DD; ++k) s = fmaf(row[k], Wr[k * DD + j], s);
        Prel[rr * DD + j] = s;
    }
}

// out[t] = Psrc[fs(t)] + Prel[rel(t)] + Pdst[fd(t)]
// Block = 256 threads = 4 waves; block covers 64 rows, 8 rows per thread.
// Row ownership is arranged so that at each step i the EVEN half-wave
// (lanes 0..31) writes row R+2i and the ODD half-wave (lanes 32..63) writes
// row R+2i+1: every wave nt-store is one contiguous 1 KiB extent (same shape
// as the 6.5 TB/s fill kernel), instead of two 512 B chunks 8 rows apart.
// Indices come pre-packed from the pk array (2 MB, L2-resident; broadcast
// int4 loads). Prel has only 2 rows: both loaded per-thread and selected with
// cndmask instead of gathered. nt stores keep the 268 MB output stream from
// evicting the hot P-tables in L2 (verified +5 us in the R4 A/B).
__global__ __launch_bounds__(256) void gather_add(
    const int* __restrict__ pk,
    const vfloat4* __restrict__ Psrc, const vfloat4* __restrict__ Pdst,
    const vfloat4* __restrict__ Prel, vfloat4* __restrict__ out) {
    int tid  = threadIdx.x;
    int lane = tid & 31;                 // which float4 of the 128-dim row
    int grp  = tid >> 5;                 // 0..7
    int w    = grp >> 1;                 // wave id 0..3
    int par  = grp & 1;                  // half-wave parity
    int rowBase = blockIdx.x * 64 + w * 16;   // this wave's 16 rows

    // pk for the wave's 16 rows (4 broadcast int4 loads).
    vint4 k0 = ((const vint4*)pk)[(rowBase >> 2) + 0];
    vint4 k1 = ((const vint4*)pk)[(rowBase >> 2) + 1];
    vint4 k2 = ((const vint4*)pk)[(rowBase >> 2) + 2];
    vint4 k3 = ((const vint4*)pk)[(rowBase >> 2) + 3];
    // Both rel rows (incl. bias) live in L1/L2 — load once, select per row.
    vfloat4 rel0 = Prel[lane];
    vfloat4 rel1 = Prel[32 + lane];

    int p16[16] = {k0[0], k0[1], k0[2], k0[3], k1[0], k1[1], k1[2], k1[3],
                   k2[0], k2[1], k2[2], k2[3], k3[0], k3[1], k3[2], k3[3]};

    // This thread owns rows rowBase + 2i + par, i = 0..7.
    int p[8];
#pragma unroll
    for (int i = 0; i < 8; ++i) p[i] = p16[2 * i + par];

    vfloat4 a[8], c[8];
#pragma unroll
    for (int i = 0; i < 8; ++i) a[i] = Psrc[(p[i] & 1023) * 32 + lane];
#pragma unroll
    for (int i = 0; i < 8; ++i) c[i] = Pdst[((p[i] >> 10) & 1023) * 32 + lane];

#pragma unroll
    for (int i = 0; i < 8; ++i) {
        vfloat4 o = a[i] + c[i] + ((p[i] >> 20) ? rel1 : rel0);
        // Wave-contiguous 1 KiB nt store: rows rowBase+2i | rowBase+2i+1.
        __builtin_nontemporal_store(
            o, &out[(rowBase + 2 * i + par) * 32 + lane]);
    }
}

extern "C" void kernel_launch(void* const* d_in, const int* in_sizes, int n_in,
                              void* d_out, int out_size, void* d_ws, size_t ws_size,
                              hipStream_t stream) {
    const float* gate_emb = (const float*)d_in[0];
    const float* edge_emb = (const float*)d_in[1];
    const float* W        = (const float*)d_in[2];
    const float* b        = (const float*)d_in[3];
    const int* src_idx    = (const int*)d_in[4];
    const int* src_type   = (const int*)d_in[5];
    const int* rel        = (const int*)d_in[6];
    const int* dst_idx    = (const int*)d_in[7];
    const int* dst_type   = (const int*)d_in[8];
    // d_in[9], d_in[10]: num_input_nodes / num_output_nodes == 256 (fixed)

    float* ws   = (float*)d_ws;
    float* Wt   = ws + WT_OFF;
    float* Psrc = ws + PSRC_OFF;
    float* Pdst = ws + PDST_OFF;
    float* Prel = ws + PREL_OFF;
    int*   pk   = (int*)(ws + PK_OFF);

    // pre: 128 transpose blocks + T/(128*4)=1024 pack blocks, one dispatch.
    pre<<<DD + T_TOTAL / (DD * 4), DD, 0, stream>>>(
        W, Wt, src_idx, src_type, rel, dst_idx, dst_type, pk);
    prep<<<NROWS + 2, DD, 0, stream>>>(gate_emb, edge_emb, b, Wt,
                                       Psrc, Pdst, Prel);
    gather_add<<<T_TOTAL / 64, 256, 0, stream>>>(
        pk, (const vfloat4*)Psrc, (const vfloat4*)Pdst,
        (const vfloat4*)Prel, (vfloat4*)d_out);
}